// Round 8
// baseline (512.837 us; speedup 1.0000x reference)
//
#include <hip/hip_runtime.h>
#include <math.h>

#define B_ROWS   1024
#define IN_FEAT  76800
#define OUT_FEAT 10
#define NF4      (IN_FEAT / 4)        // 19200 i8-quad groups (float4) per row
#define W_ELEMS  (OUT_FEAT * IN_FEAT) // 768000
#define EPSQ     1e-5f
// 512-thread streaming kernels: 19200 = 512*37 + 256
#define NJ_FULL  37
#define TAIL_N   256

#if __has_builtin(__builtin_amdgcn_sdot4)
#define SDOT4(a, b, c) __builtin_amdgcn_sdot4((int)(a), (int)(b), (c), false)
#else
__device__ __forceinline__ int sdot4_sw(unsigned a, unsigned b, int c) {
    #pragma unroll
    for (int i = 0; i < 4; ++i)
        c += (int)(signed char)(a >> (8 * i)) * (int)(signed char)(b >> (8 * i));
    return c;
}
#define SDOT4(a, b, c) sdot4_sw((a), (b), (c))
#endif

// ---------------- K1: per-block partial sums of |W| ----------------
__global__ __launch_bounds__(256) void k_wabs_partial(const float* __restrict__ W,
                                                      float* __restrict__ partials) {
    const int tid = threadIdx.x, bid = blockIdx.x;
    float s = 0.f;
    for (int i = bid * 256 + tid; i < W_ELEMS; i += 256 * 256) s += fabsf(W[i]);
    #pragma unroll
    for (int off = 32; off >= 1; off >>= 1) s += __shfl_down(s, off, 64);
    __shared__ float red[4];
    const int wv = tid >> 6, ln = tid & 63;
    if (ln == 0) red[wv] = s;
    __syncthreads();
    if (tid == 0) partials[bid] = red[0] + red[1] + red[2] + red[3];
}

// ---------------- K2: final reduce -> scale_w = 1/clip(mean|W|, eps) ----------------
__global__ __launch_bounds__(256) void k_wscale(const float* __restrict__ partials,
                                                float* __restrict__ scale_w) {
    const int tid = threadIdx.x;
    float s = partials[tid];
    #pragma unroll
    for (int off = 32; off >= 1; off >>= 1) s += __shfl_down(s, off, 64);
    __shared__ float red[4];
    const int wv = tid >> 6, ln = tid & 63;
    if (ln == 0) red[wv] = s;
    __syncthreads();
    if (tid == 0) {
        float mean = (red[0] + red[1] + red[2] + red[3]) / (float)W_ELEMS;
        scale_w[0] = 1.0f / fmaxf(mean, EPSQ);
    }
}

// ---------------- K3: ternary-quantize weights into SIGNED i8 quad planes ----------------
// Group g (elements 4g..4g+3): wa[g] = outputs 0..3, wb[g] = outputs 4..7,
// wc[g] = outputs 8..9. Each u32 = 4 signed-i8 codes in {-1,0,1} (v_dot4 operands).
__global__ __launch_bounds__(256) void k_wpackdot(const float* __restrict__ W,
                                                  const float* __restrict__ scale_w,
                                                  uint4* __restrict__ wa,
                                                  uint4* __restrict__ wb,
                                                  uint2* __restrict__ wc) {
    const int g = blockIdx.x * 256 + threadIdx.x;
    if (g >= NF4) return;
    const float s = scale_w[0];
    unsigned pk[OUT_FEAT];
    #pragma unroll
    for (int o = 0; o < OUT_FEAT; ++o) {
        const float4 wv = *(const float4*)(W + (size_t)o * IN_FEAT + 4 * g);
        int c0 = (int)fminf(1.f, fmaxf(-1.f, rintf(wv.x * s)));
        int c1 = (int)fminf(1.f, fmaxf(-1.f, rintf(wv.y * s)));
        int c2 = (int)fminf(1.f, fmaxf(-1.f, rintf(wv.z * s)));
        int c3 = (int)fminf(1.f, fmaxf(-1.f, rintf(wv.w * s)));
        pk[o] = (unsigned)(c0 & 255) | ((unsigned)(c1 & 255) << 8) |
                ((unsigned)(c2 & 255) << 16) | ((unsigned)(c3 & 255) << 24);
    }
    wa[g] = make_uint4(pk[0], pk[1], pk[2], pk[3]);
    wb[g] = make_uint4(pk[4], pk[5], pk[6], pk[7]);
    wc[g] = make_uint2(pk[8], pk[9]);
}

// ---------------- K4: per-row absmax -> sx[row] = 127/clip(max|x|, eps) ----------------
// 512 thr x 1024 blocks = 32 waves/CU: pure full-occupancy HBM stream.
__global__ __launch_bounds__(512) void k_rowmax(const float* __restrict__ x,
                                                float* __restrict__ sxrow) {
    const int tid = threadIdx.x, row = blockIdx.x;
    const float4* __restrict__ xr = (const float4*)(x + (size_t)row * IN_FEAT);
    float m = 0.f;
    #pragma unroll 4
    for (int j = 0; j < NJ_FULL; ++j) {
        float4 v = xr[tid + j * 512];
        m = fmaxf(m, fmaxf(fmaxf(fabsf(v.x), fabsf(v.y)), fmaxf(fabsf(v.z), fabsf(v.w))));
    }
    if (tid < TAIL_N) {
        float4 v = xr[NJ_FULL * 512 + tid];
        m = fmaxf(m, fmaxf(fmaxf(fabsf(v.x), fabsf(v.y)), fmaxf(fabsf(v.z), fabsf(v.w))));
    }
    #pragma unroll
    for (int off = 32; off >= 1; off >>= 1) m = fmaxf(m, __shfl_down(m, off, 64));
    __shared__ float red[8];
    const int wv = tid >> 6, ln = tid & 63;
    if (ln == 0) red[wv] = m;
    __syncthreads();
    if (tid == 0) {
        float mm = red[0];
        #pragma unroll
        for (int i = 1; i < 8; ++i) mm = fmaxf(mm, red[i]);
        sxrow[row] = 127.0f / fmaxf(mm, EPSQ);
    }
}

// ---------------- K5: streaming quantize + dot4 GEMV + softmax, one row/block ----------------
// 512 thr x 1024 blocks = 32 waves/CU streaming x once (sx known). Per 4 elements:
// 4 VMEM + ~28 VALU incl. 10 v_dot4_i32_i8 -> issue cost hides under the HBM stream.
// Signed codes -> exact int accumulate, no sum_q correction, no atomics.
// Row order REVERSED vs dispatch so early blocks hit rowmax's L3 residue (round-4 +5us).
__global__ __launch_bounds__(512) void k_gemv(const float* __restrict__ x,
                                              const uint4* __restrict__ wa,
                                              const uint4* __restrict__ wb,
                                              const uint2* __restrict__ wc,
                                              const float* __restrict__ bias,
                                              const float* __restrict__ scale_w,
                                              const float* __restrict__ sxrow,
                                              float* __restrict__ out) {
    __shared__ int   racc[8][OUT_FEAT];
    __shared__ int   fin[OUT_FEAT];
    __shared__ float lgs[OUT_FEAT];

    const int tid = threadIdx.x;
    const int row = (B_ROWS - 1) - blockIdx.x;          // reversed
    const float sx = sxrow[row];
    const float sw = scale_w[0];
    const float4* __restrict__ xr = (const float4*)(x + (size_t)row * IN_FEAT);

    int acc[OUT_FEAT] = {0, 0, 0, 0, 0, 0, 0, 0, 0, 0};

    #pragma unroll 2
    for (int j = 0; j <= NJ_FULL; ++j) {
        const int idx = tid + j * 512;
        if (j < NJ_FULL || tid < TAIL_N) {              // tail: 19200 = 512*37 + 256
            float4 v = xr[idx];
            int q0 = (int)rintf(v.x * sx);              // |x*sx| <= 127: fits i8
            int q1 = (int)rintf(v.y * sx);
            int q2 = (int)rintf(v.z * sx);
            int q3 = (int)rintf(v.w * sx);
            unsigned qp = (unsigned)(q0 & 255) | ((unsigned)(q1 & 255) << 8) |
                          ((unsigned)(q2 & 255) << 16) | ((unsigned)(q3 & 255) << 24);
            uint4 a  = wa[idx];
            uint4 b  = wb[idx];
            uint2 c2 = wc[idx];
            acc[0] = SDOT4(qp, a.x, acc[0]);
            acc[1] = SDOT4(qp, a.y, acc[1]);
            acc[2] = SDOT4(qp, a.z, acc[2]);
            acc[3] = SDOT4(qp, a.w, acc[3]);
            acc[4] = SDOT4(qp, b.x, acc[4]);
            acc[5] = SDOT4(qp, b.y, acc[5]);
            acc[6] = SDOT4(qp, b.z, acc[6]);
            acc[7] = SDOT4(qp, b.w, acc[7]);
            acc[8] = SDOT4(qp, c2.x, acc[8]);
            acc[9] = SDOT4(qp, c2.y, acc[9]);
        }
    }

    // ---- block reduce 10 int accumulators across 8 waves ----
    #pragma unroll
    for (int t = 0; t < OUT_FEAT; ++t) {
        #pragma unroll
        for (int off = 32; off >= 1; off >>= 1) acc[t] += __shfl_down(acc[t], off, 64);
    }
    const int wv = tid >> 6, ln = tid & 63;
    if (ln == 0) {
        #pragma unroll
        for (int t = 0; t < OUT_FEAT; ++t) racc[wv][t] = acc[t];
    }
    __syncthreads();
    if (tid < OUT_FEAT) {
        int s = 0;
        #pragma unroll
        for (int w2 = 0; w2 < 8; ++w2) s += racc[w2][tid];
        fin[tid] = s;
    }
    __syncthreads();
    if (tid < OUT_FEAT) {
        const float inv = 1.0f / (sx * sw);             // dequant: sum q*c / (sx*sw)
        lgs[tid] = (float)fin[tid] * inv + bias[tid];
    }
    __syncthreads();
    if (tid < OUT_FEAT) {
        float mx = lgs[0];
        #pragma unroll
        for (int o = 1; o < OUT_FEAT; ++o) mx = fmaxf(mx, lgs[o]);
        float den = 0.f;
        #pragma unroll
        for (int o = 0; o < OUT_FEAT; ++o) den += __expf(lgs[o] - mx);
        float e = __expf(lgs[tid] - mx);
        out[row * OUT_FEAT + tid] = e / den;
    }
}

extern "C" void kernel_launch(void* const* d_in, const int* in_sizes, int n_in,
                              void* d_out, int out_size, void* d_ws, size_t ws_size,
                              hipStream_t stream) {
    const float* x    = (const float*)d_in[0];
    const float* Wmat = (const float*)d_in[1];
    const float* bias = (const float*)d_in[2];
    float* out = (float*)d_out;

    char* wsb = (char*)d_ws;
    float* scale_w  = (float*)wsb;                       // 1 float
    float* partials = (float*)(wsb + 256);               // 256 floats
    float* sxrow    = (float*)(wsb + 2048);              // 1024 floats
    uint4* wa       = (uint4*)(wsb + 8192);              // 19200 uint4 = 307200 B
    uint4* wb       = (uint4*)(wsb + 8192 + 307200);     // 307200 B
    uint2* wc       = (uint2*)(wsb + 8192 + 614400);     // 153600 B (total ~776 KB)

    k_wabs_partial<<<256, 256, 0, stream>>>(Wmat, partials);
    k_wscale<<<1, 256, 0, stream>>>(partials, scale_w);
    k_wpackdot<<<(NF4 + 255) / 256, 256, 0, stream>>>(Wmat, scale_w, wa, wb, wc);
    k_rowmax<<<B_ROWS, 512, 0, stream>>>(x, sxrow);
    k_gemv<<<B_ROWS, 512, 0, stream>>>(x, wa, wb, wc, bias, scale_w, sxrow, out);
}